// Round 1
// baseline (377.072 us; speedup 1.0000x reference)
//
#include <hip/hip_runtime.h>

typedef unsigned short u16;
typedef unsigned int u32;
typedef __attribute__((ext_vector_type(8))) short short8;
typedef __attribute__((ext_vector_type(4))) float f32x4;

#define NEG (-1e30f)

// Problem sizes
#define B_N 16
#define T_N 500
#define E_N 1024
#define V_N 4000
#define L_N 100
#define S_N 201      // 2L+1
#define M_P 8064     // 63*128 padded rows
#define N_P 4096     // 32*128 padded vocab
#define LLP 104      // lab_lp row stride (blank + 100 labels, padded)

// ws layout (bytes)
#define OFF_A   0
#define OFF_BT  16515072UL   // 8064*1024*2
#define OFF_C   24903680UL   // + 4096*1024*2
#define OFF_LAB 90963968UL   // + 8064*4096*2

__device__ __forceinline__ u16 f2bf(float f) {
  u32 u = __float_as_uint(f);
  u += 0x7fffu + ((u >> 16) & 1u);   // RNE
  return (u16)(u >> 16);
}
__device__ __forceinline__ float bf2f(u16 h) {
  return __uint_as_float(((u32)h) << 16);
}
__device__ __forceinline__ float lse2f(float x, float y) {
  float m = fmaxf(x, y);
  return m + __logf(__expf(x - m) + __expf(y - m));
}
__device__ __forceinline__ float lse3f(float x, float y, float z) {
  float m = fmaxf(fmaxf(x, y), z);
  return m + __logf(__expf(x - m) + __expf(y - m) + __expf(z - m));
}

// K1: cast hs [8000][1024] f32 -> A bf16 [8064][1024] (pad rows zero); zero d_out
__global__ __launch_bounds__(256) void castA(const float* __restrict__ hs,
                                             u16* __restrict__ A,
                                             float* __restrict__ out) {
  int idx = blockIdx.x * 256 + threadIdx.x;   // < 2064384 (float4 groups)
  if (idx == 0) out[0] = 0.f;
  int row = idx >> 8;                          // (idx*4) >> 10
  float4 x;
  if (row < B_N * T_N) x = ((const float4*)hs)[idx];
  else x = make_float4(0.f, 0.f, 0.f, 0.f);
  ushort4 o;
  o.x = f2bf(x.x); o.y = f2bf(x.y); o.z = f2bf(x.z); o.w = f2bf(x.w);
  ((ushort4*)A)[idx] = o;
}

// K2: transpose-cast W [1024][4000] f32 -> Bt bf16 [4096][1024] (pad cols zero)
__global__ __launch_bounds__(256) void castB(const float* __restrict__ W,
                                             u16* __restrict__ Bt) {
  __shared__ float tile[32][33];
  int v0 = blockIdx.x * 32;   // vocab
  int e0 = blockIdx.y * 32;   // embed
  int tx = threadIdx.x & 31, ty = threadIdx.x >> 5;  // 32 x 8
#pragma unroll
  for (int i = 0; i < 4; ++i) {
    int e = e0 + ty * 4 + i;
    int v = v0 + tx;
    tile[ty * 4 + i][tx] = (v < V_N) ? W[e * V_N + v] : 0.f;
  }
  __syncthreads();
#pragma unroll
  for (int i = 0; i < 4; ++i) {
    int vloc = ty * 4 + i;
    Bt[(size_t)(v0 + vloc) * 1024 + (e0 + tx)] = f2bf(tile[tx][vloc]);
  }
}

// K3: 128x128x32 bf16 MFMA GEMM, C = A * Bt^T  (logits, stored bf16, no bias)
__global__ __launch_bounds__(256, 2) void gemm_bf16(const u16* __restrict__ A,
                                                    const u16* __restrict__ Bt,
                                                    u16* __restrict__ C) {
  __shared__ __align__(16) u16 As[128 * 32];
  __shared__ __align__(16) u16 Bs[128 * 32];
  const int tid = threadIdx.x;
  const int lane = tid & 63;
  const int w = tid >> 6;          // wave 0..3
  const int wm = w >> 1, wn = w & 1;
  const size_t m0 = (size_t)blockIdx.y * 128;
  const size_t n0 = (size_t)blockIdx.x * 128;

  // staging: each wave stages a 32-row slab (2 x 16 rows) of A and of Bt
  const int sr = lane >> 2;            // 0..15
  const int sc = (lane & 3) << 3;      // 0,8,16,24 (bf16 elems)
  const u16* gA = A + (m0 + (size_t)(w * 32 + sr)) * 1024 + sc;
  const u16* gB = Bt + (n0 + (size_t)(w * 32 + sr)) * 1024 + sc;
  u16* sA = &As[(w * 32) * 32];
  u16* sB = &Bs[(w * 32) * 32];

  f32x4 acc[4][4];
#pragma unroll
  for (int i = 0; i < 4; ++i)
#pragma unroll
    for (int j = 0; j < 4; ++j) acc[i][j] = (f32x4){0.f, 0.f, 0.f, 0.f};

  const int fr = lane & 15;
  const int fq = (lane >> 4) << 3;     // k offset 0/8/16/24
  const u16* rA = &As[(wm * 64 + fr) * 32 + fq];
  const u16* rB = &Bs[(wn * 64 + fr) * 32 + fq];

  for (int kt = 0; kt < 1024; kt += 32) {
#pragma unroll
    for (int u = 0; u < 2; ++u) {
      __builtin_amdgcn_global_load_lds(
          (const __attribute__((address_space(1))) void*)(gA + u * 16 * 1024 + kt),
          (__attribute__((address_space(3))) void*)(sA + u * 16 * 32), 16, 0, 0);
      __builtin_amdgcn_global_load_lds(
          (const __attribute__((address_space(1))) void*)(gB + u * 16 * 1024 + kt),
          (__attribute__((address_space(3))) void*)(sB + u * 16 * 32), 16, 0, 0);
    }
    __syncthreads();   // drains vmcnt before barrier (compiler-inserted)
    short8 af[4], bfr[4];
#pragma unroll
    for (int i = 0; i < 4; ++i) af[i] = *(const short8*)(rA + i * 16 * 32);
#pragma unroll
    for (int j = 0; j < 4; ++j) bfr[j] = *(const short8*)(rB + j * 16 * 32);
#pragma unroll
    for (int i = 0; i < 4; ++i)
#pragma unroll
      for (int j = 0; j < 4; ++j)
        acc[i][j] = __builtin_amdgcn_mfma_f32_16x16x32_bf16(af[i], bfr[j],
                                                            acc[i][j], 0, 0, 0);
    __syncthreads();
  }

  // C/D layout (m89-verified): col = lane&15 (N), row = (lane>>4)*4 + reg (M)
  const int cq = lane >> 4;
  const int cc = lane & 15;
#pragma unroll
  for (int i = 0; i < 4; ++i)
#pragma unroll
    for (int j = 0; j < 4; ++j) {
      size_t rr = m0 + wm * 64 + i * 16 + cq * 4;
      size_t nn = n0 + wn * 64 + j * 16 + cc;
      u16* o = C + rr * N_P + nn;
#pragma unroll
      for (int g = 0; g < 4; ++g) o[(size_t)g * N_P] = f2bf(acc[i][j][g]);
    }
}

// K4: per-row logsumexp over V + gather label log-probs -> lab_lp [8000][104]
__global__ __launch_bounds__(256) void rowstat(const u16* __restrict__ C,
                                               const float* __restrict__ bias,
                                               const int* __restrict__ ys,
                                               float* __restrict__ lab) {
  int r = blockIdx.x;          // 0..7999
  int tid = threadIdx.x;
  const u16* row = C + (size_t)r * N_P;
  float v[16];
  float mx = NEG;
#pragma unroll
  for (int u = 0; u < 16; ++u) {
    int c = tid + (u << 8);
    float x = (c < V_N) ? bf2f(row[c]) + bias[c] : NEG;
    v[u] = x;
    mx = fmaxf(mx, x);
  }
#pragma unroll
  for (int o = 32; o > 0; o >>= 1) mx = fmaxf(mx, __shfl_xor(mx, o));
  __shared__ float sm[4], ss[4];
  int w = tid >> 6;
  if ((tid & 63) == 0) sm[w] = mx;
  __syncthreads();
  mx = fmaxf(fmaxf(sm[0], sm[1]), fmaxf(sm[2], sm[3]));
  float s = 0.f;
#pragma unroll
  for (int u = 0; u < 16; ++u) s += __expf(v[u] - mx);
#pragma unroll
  for (int o = 32; o > 0; o >>= 1) s += __shfl_xor(s, o);
  if ((tid & 63) == 0) ss[w] = s;
  __syncthreads();
  float lse = mx + __logf(ss[0] + ss[1] + ss[2] + ss[3]);
  if (tid < 1 + L_N) {
    int b = r / T_N;
    int lab_id = (tid == 0) ? 0 : max(ys[b * L_N + tid - 1], 0);
    lab[(size_t)r * LLP + tid] = bf2f(row[lab_id]) + bias[lab_id] - lse;
  }
}

// K5: CTC forward DP. One wave per batch, 4 states/lane (S=201 <= 256).
__global__ __launch_bounds__(64) void ctc_dp(const float* __restrict__ lab,
                                             const int* __restrict__ ys,
                                             const int* __restrict__ ilens,
                                             const int* __restrict__ olens,
                                             float* __restrict__ out) {
  int b = blockIdx.x;
  int lane = threadIdx.x;
  const float* base = lab + (size_t)b * T_N * LLP;
  int slot[4];
  bool allow[4], valid[4];
#pragma unroll
  for (int j = 0; j < 4; ++j) {
    int s = j * 64 + lane;
    valid[j] = (s < S_N);
    slot[j] = (valid[j] && (s & 1)) ? (1 + (s >> 1)) : 0;
    allow[j] = false;
    if (valid[j] && (s & 1)) {
      int k = s >> 1;
      int yk = max(ys[b * L_N + k], 0);
      int yp = (k > 0) ? max(ys[b * L_N + k - 1], 0) : -1;
      allow[j] = (yk != 0) && (yk != yp);
    }
  }
  float a[4];
#pragma unroll
  for (int j = 0; j < 4; ++j) {
    int s = j * 64 + lane;
    a[j] = (s <= 1) ? base[slot[j]] : NEG;
  }
  int il = ilens[b];
  float lpc[4];
#pragma unroll
  for (int j = 0; j < 4; ++j) lpc[j] = base[LLP + slot[j]];  // t=1 (il >= 250)
  for (int t = 1; t < il; ++t) {
    int tn = (t + 1 < il) ? t + 1 : t;
    float lpn[4];
#pragma unroll
    for (int j = 0; j < 4; ++j) lpn[j] = base[(size_t)tn * LLP + slot[j]];
    float na[4];
#pragma unroll
    for (int j = 0; j < 4; ++j) {
      float up1 = __shfl_up(a[j], 1);
      float c1 = (j > 0) ? __shfl(a[j - 1], 63) : NEG;
      float am1 = (lane == 0) ? c1 : up1;
      float up2 = __shfl_up(a[j], 2);
      int sl = 62 + (lane & 1);
      float c2 = (j > 0) ? __shfl(a[j - 1], sl) : NEG;
      float am2 = (lane < 2) ? c2 : up2;
      am2 = allow[j] ? am2 : NEG;
      na[j] = lse3f(a[j], am1, am2) + lpc[j];
    }
#pragma unroll
    for (int j = 0; j < 4; ++j) {
      a[j] = valid[j] ? na[j] : NEG;
      lpc[j] = lpn[j];
    }
  }
  int ol = olens[b];
  int s1 = 2 * ol, s2 = 2 * ol - 1;
  float x1, x2;
  {
    int j = s1 >> 6, l = s1 & 63;
    float t0 = (j == 0) ? a[0] : (j == 1) ? a[1] : (j == 2) ? a[2] : a[3];
    x1 = __shfl(t0, l);
  }
  {
    int j = s2 >> 6, l = s2 & 63;
    float t0 = (j == 0) ? a[0] : (j == 1) ? a[1] : (j == 2) ? a[2] : a[3];
    x2 = __shfl(t0, l);
  }
  float ll = lse2f(x1, x2);
  if (lane == 0) atomicAdd(out, -ll * (1.0f / B_N));
}

extern "C" void kernel_launch(void* const* d_in, const int* in_sizes, int n_in,
                              void* d_out, int out_size, void* d_ws, size_t ws_size,
                              hipStream_t stream) {
  const float* hs    = (const float*)d_in[0];
  const float* W     = (const float*)d_in[1];
  const float* bias  = (const float*)d_in[2];
  const int*   ys    = (const int*)d_in[3];
  const int*   ilens = (const int*)d_in[4];
  const int*   olens = (const int*)d_in[5];
  char* ws = (char*)d_ws;
  u16*   A   = (u16*)(ws + OFF_A);
  u16*   Bt  = (u16*)(ws + OFF_BT);
  u16*   C   = (u16*)(ws + OFF_C);
  float* lab = (float*)(ws + OFF_LAB);
  float* out = (float*)d_out;

  castA<<<M_P * E_N / (256 * 4), 256, 0, stream>>>(hs, A, out);
  castB<<<dim3(N_P / 32, E_N / 32), 256, 0, stream>>>(W, Bt);
  gemm_bf16<<<dim3(N_P / 128, M_P / 128), 256, 0, stream>>>(A, Bt, C);
  rowstat<<<B_N * T_N, 256, 0, stream>>>(C, bias, ys, lab);
  ctc_dp<<<B_N, 64, 0, stream>>>(lab, ys, ilens, olens, out);
}

// Round 3
// 330.768 us; speedup vs baseline: 1.1400x; 1.1400x over previous
//
#include <hip/hip_runtime.h>

typedef unsigned short u16;
typedef unsigned int u32;
typedef __attribute__((ext_vector_type(8))) short short8;
typedef __attribute__((ext_vector_type(4))) float f32x4;

#define NEG (-1e30f)
#define LN2 0.6931471805599453f
#define INV_LN2 1.4426950408889634f

// Problem sizes
#define B_N 16
#define T_N 500
#define E_N 1024
#define V_N 4000
#define L_N 100
#define S_N 201      // 2L+1
#define M_P 8064     // 63*128 padded rows
#define N_P 4096     // 32*128 padded vocab
#define LLP 104      // lab_lp row stride (blank + 100 labels, padded)

// ws layout (bytes)
#define OFF_A   0
#define OFF_BT  16515072UL   // 8064*1024*2
#define OFF_C   24903680UL   // + 4096*1024*2
#define OFF_LAB 90963968UL   // + 8064*4096*2

__device__ __forceinline__ u16 f2bf(float f) {
  u32 u = __float_as_uint(f);
  u += 0x7fffu + ((u >> 16) & 1u);   // RNE
  return (u16)(u >> 16);
}
__device__ __forceinline__ float bf2f(u16 h) {
  return __uint_as_float(((u32)h) << 16);
}
// log2-domain logaddexp: 2 transcendentals (exp2f -> native v_exp_f32)
__device__ __forceinline__ float lse2_2(float x, float y) {
  float m = fmaxf(x, y);
  float d = -fabsf(x - y);
  return m + __log2f(1.0f + exp2f(d));
}
// log2-domain 3-way logaddexp: 4 transcendentals
__device__ __forceinline__ float lse3_2(float x, float y, float z) {
  float m = fmaxf(fmaxf(x, y), z);
  return m + __log2f(exp2f(x - m) + exp2f(y - m) + exp2f(z - m));
}

// K1: cast hs [8000][1024] f32 -> A bf16 [8064][1024] (pad rows zero); zero d_out
__global__ __launch_bounds__(256) void castA(const float* __restrict__ hs,
                                             u16* __restrict__ A,
                                             float* __restrict__ out) {
  int idx = blockIdx.x * 256 + threadIdx.x;   // < 2064384 (float4 groups)
  if (idx == 0) out[0] = 0.f;
  int row = idx >> 8;                          // (idx*4) >> 10
  float4 x;
  if (row < B_N * T_N) x = ((const float4*)hs)[idx];
  else x = make_float4(0.f, 0.f, 0.f, 0.f);
  ushort4 o;
  o.x = f2bf(x.x); o.y = f2bf(x.y); o.z = f2bf(x.z); o.w = f2bf(x.w);
  ((ushort4*)A)[idx] = o;
}

// K2: transpose-cast W [1024][4000] f32 -> Bt bf16 [4096][1024] (pad cols zero)
__global__ __launch_bounds__(256) void castB(const float* __restrict__ W,
                                             u16* __restrict__ Bt) {
  __shared__ float tile[32][33];
  int v0 = blockIdx.x * 32;   // vocab
  int e0 = blockIdx.y * 32;   // embed
  int tx = threadIdx.x & 31, ty = threadIdx.x >> 5;  // 32 x 8
#pragma unroll
  for (int i = 0; i < 4; ++i) {
    int e = e0 + ty * 4 + i;
    int v = v0 + tx;
    tile[ty * 4 + i][tx] = (v < V_N) ? W[e * V_N + v] : 0.f;
  }
  __syncthreads();
#pragma unroll
  for (int i = 0; i < 4; ++i) {
    int vloc = ty * 4 + i;
    Bt[(size_t)(v0 + vloc) * 1024 + (e0 + tx)] = f2bf(tile[tx][vloc]);
  }
}

// K3: 128x128x32 bf16 MFMA GEMM, C = A * Bt^T  (logits, stored bf16, no bias)
__global__ __launch_bounds__(256, 2) void gemm_bf16(const u16* __restrict__ A,
                                                    const u16* __restrict__ Bt,
                                                    u16* __restrict__ C) {
  __shared__ __align__(16) u16 As[128 * 32];
  __shared__ __align__(16) u16 Bs[128 * 32];
  const int tid = threadIdx.x;
  const int lane = tid & 63;
  const int w = tid >> 6;          // wave 0..3
  const int wm = w >> 1, wn = w & 1;
  const size_t m0 = (size_t)blockIdx.y * 128;
  const size_t n0 = (size_t)blockIdx.x * 128;

  const int sr = lane >> 2;            // 0..15
  const int sc = (lane & 3) << 3;      // 0,8,16,24 (bf16 elems)
  const u16* gA = A + (m0 + (size_t)(w * 32 + sr)) * 1024 + sc;
  const u16* gB = Bt + (n0 + (size_t)(w * 32 + sr)) * 1024 + sc;
  u16* sA = &As[(w * 32) * 32];
  u16* sB = &Bs[(w * 32) * 32];

  f32x4 acc[4][4];
#pragma unroll
  for (int i = 0; i < 4; ++i)
#pragma unroll
    for (int j = 0; j < 4; ++j) acc[i][j] = (f32x4){0.f, 0.f, 0.f, 0.f};

  const int fr = lane & 15;
  const int fq = (lane >> 4) << 3;     // k offset 0/8/16/24
  const u16* rA = &As[(wm * 64 + fr) * 32 + fq];
  const u16* rB = &Bs[(wn * 64 + fr) * 32 + fq];

  for (int kt = 0; kt < 1024; kt += 32) {
#pragma unroll
    for (int u = 0; u < 2; ++u) {
      __builtin_amdgcn_global_load_lds(
          (const __attribute__((address_space(1))) void*)(gA + u * 16 * 1024 + kt),
          (__attribute__((address_space(3))) void*)(sA + u * 16 * 32), 16, 0, 0);
      __builtin_amdgcn_global_load_lds(
          (const __attribute__((address_space(1))) void*)(gB + u * 16 * 1024 + kt),
          (__attribute__((address_space(3))) void*)(sB + u * 16 * 32), 16, 0, 0);
    }
    __syncthreads();
    short8 af[4], bfr[4];
#pragma unroll
    for (int i = 0; i < 4; ++i) af[i] = *(const short8*)(rA + i * 16 * 32);
#pragma unroll
    for (int j = 0; j < 4; ++j) bfr[j] = *(const short8*)(rB + j * 16 * 32);
#pragma unroll
    for (int i = 0; i < 4; ++i)
#pragma unroll
      for (int j = 0; j < 4; ++j)
        acc[i][j] = __builtin_amdgcn_mfma_f32_16x16x32_bf16(af[i], bfr[j],
                                                            acc[i][j], 0, 0, 0);
    __syncthreads();
  }

  const int cq = lane >> 4;
  const int cc = lane & 15;
#pragma unroll
  for (int i = 0; i < 4; ++i)
#pragma unroll
    for (int j = 0; j < 4; ++j) {
      size_t rr = m0 + wm * 64 + i * 16 + cq * 4;
      size_t nn = n0 + wn * 64 + j * 16 + cc;
      u16* o = C + rr * N_P + nn;
#pragma unroll
      for (int g = 0; g < 4; ++g) o[(size_t)g * N_P] = f2bf(acc[i][j][g]);
    }
}

// K4: per-row logsumexp over V + gather label log-probs -> lab_lp [8000][104]
// Output is scaled by 1/ln2 (log2 domain) for the DP kernel.
__global__ __launch_bounds__(256) void rowstat(const u16* __restrict__ C,
                                               const float* __restrict__ bias,
                                               const int* __restrict__ ys,
                                               float* __restrict__ lab) {
  int r = blockIdx.x;          // 0..7999
  int tid = threadIdx.x;
  const u16* row = C + (size_t)r * N_P;
  float v[16];
  float mx = NEG;
#pragma unroll
  for (int u = 0; u < 16; ++u) {
    int c = tid + (u << 8);
    float x = (c < V_N) ? bf2f(row[c]) + bias[c] : NEG;
    v[u] = x;
    mx = fmaxf(mx, x);
  }
#pragma unroll
  for (int o = 32; o > 0; o >>= 1) mx = fmaxf(mx, __shfl_xor(mx, o));
  __shared__ float sm[4], ss[4];
  int w = tid >> 6;
  if ((tid & 63) == 0) sm[w] = mx;
  __syncthreads();
  mx = fmaxf(fmaxf(sm[0], sm[1]), fmaxf(sm[2], sm[3]));
  float s = 0.f;
#pragma unroll
  for (int u = 0; u < 16; ++u) s += __expf(v[u] - mx);
#pragma unroll
  for (int o = 32; o > 0; o >>= 1) s += __shfl_xor(s, o);
  if ((tid & 63) == 0) ss[w] = s;
  __syncthreads();
  float lse = mx + __logf(ss[0] + ss[1] + ss[2] + ss[3]);
  if (tid < 1 + L_N) {
    int b = r / T_N;
    int lab_id = (tid == 0) ? 0 : max(ys[b * L_N + tid - 1], 0);
    lab[(size_t)r * LLP + tid] = (bf2f(row[lab_id]) + bias[lab_id] - lse) * INV_LN2;
  }
}

// K5: CTC forward DP, log2 domain. One wave per batch; lane L holds states
// 4L..4L+3 (blocked), so shifts are register-local except a3 from lane L-1
// -> exactly ONE shuffle per time step.
__global__ __launch_bounds__(64) void ctc_dp(const float* __restrict__ lab,
                                             const int* __restrict__ ys,
                                             const int* __restrict__ ilens,
                                             const int* __restrict__ olens,
                                             float* __restrict__ out) {
  int b = blockIdx.x;
  int L = threadIdx.x;
  const float* base = lab + (size_t)b * T_N * LLP;

  // label indices for this lane's odd states: s=4L+1 -> k0=2L, s=4L+3 -> k1=2L+1
  int k0 = 2 * L, k1 = 2 * L + 1;
  int k0c = min(k0, L_N - 1), k1c = min(k1, L_N - 1);
  int y0 = max(ys[b * L_N + k0c], 0);
  int y1 = max(ys[b * L_N + k1c], 0);
  int y0m = (k0 > 0) ? max(ys[b * L_N + min(k0 - 1, L_N - 1)], 0) : -1;
  bool allow1 = (y0 != 0) && (y0 != y0m);   // skip into s=4L+1 (lane 0: p3=NEG anyway)
  bool allow3 = (y1 != 0) && (y1 != y0);    // skip into s=4L+3
  int slotK0 = 1 + k0c, slotK1 = 1 + k1c;

  // t = 0 init (log2 domain): only s=0,1 live
  float a0 = (L == 0) ? base[0] : NEG;
  float a1 = (L == 0) ? base[1] : NEG;
  float a2 = NEG, a3 = NEG;

  int il = ilens[b];   // >= 250
  const float* pt = base + LLP;   // t = 1
  float lpB = pt[0], lpK0 = pt[slotK0], lpK1 = pt[slotK1];

  for (int t = 1; t < il; ++t) {
    // prefetch t+1 (consumed next iteration; full iteration to cover latency)
    const float* pn = base + (size_t)((t + 1 < il) ? t + 1 : t) * LLP;
    float nB = pn[0], nK0 = pn[slotK0], nK1 = pn[slotK1];

    float p3 = __shfl_up(a3, 1);
    if (L == 0) p3 = NEG;
    float p3m = allow1 ? p3 : NEG;
    float a1m = allow3 ? a1 : NEG;

    float n0 = lse2_2(a0, p3) + lpB;          // blank s=4L
    float n1 = lse3_2(a1, a0, p3m) + lpK0;    // label s=4L+1
    float n2 = lse2_2(a2, a1) + lpB;          // blank s=4L+2
    float n3 = lse3_2(a3, a2, a1m) + lpK1;    // label s=4L+3

    a0 = n0; a1 = n1; a2 = n2; a3 = n3;
    lpB = nB; lpK0 = nK0; lpK1 = nK1;
  }

  int ol = olens[b];
  int s1 = 2 * ol, s2 = 2 * ol - 1;   // s1 even, s2 odd; both <= 200
  int j1 = s1 & 3, j2 = s2 & 3;       // uniform across wave
  float t1 = (j1 == 0) ? a0 : a2;
  float t2 = (j2 == 1) ? a1 : a3;
  float x1 = __shfl(t1, s1 >> 2);
  float x2 = __shfl(t2, s2 >> 2);
  float ll = lse2_2(x1, x2) * LN2;    // back to natural log
  if (L == 0) atomicAdd(out, -ll * (1.0f / B_N));
}

extern "C" void kernel_launch(void* const* d_in, const int* in_sizes, int n_in,
                              void* d_out, int out_size, void* d_ws, size_t ws_size,
                              hipStream_t stream) {
  const float* hs    = (const float*)d_in[0];
  const float* W     = (const float*)d_in[1];
  const float* bias  = (const float*)d_in[2];
  const int*   ys    = (const int*)d_in[3];
  const int*   ilens = (const int*)d_in[4];
  const int*   olens = (const int*)d_in[5];
  char* ws = (char*)d_ws;
  u16*   A   = (u16*)(ws + OFF_A);
  u16*   Bt  = (u16*)(ws + OFF_BT);
  u16*   C   = (u16*)(ws + OFF_C);
  float* lab = (float*)(ws + OFF_LAB);
  float* out = (float*)d_out;

  castA<<<M_P * E_N / (256 * 4), 256, 0, stream>>>(hs, A, out);
  castB<<<dim3(N_P / 32, E_N / 32), 256, 0, stream>>>(W, Bt);
  gemm_bf16<<<dim3(N_P / 128, M_P / 128), 256, 0, stream>>>(A, Bt, C);
  rowstat<<<B_N * T_N, 256, 0, stream>>>(C, bias, ys, lab);
  ctc_dp<<<B_N, 64, 0, stream>>>(lab, ys, ilens, olens, out);
}

// Round 4
// 309.287 us; speedup vs baseline: 1.2192x; 1.0695x over previous
//
#include <hip/hip_runtime.h>

typedef unsigned short u16;
typedef unsigned int u32;
typedef __attribute__((ext_vector_type(8))) short short8;
typedef __attribute__((ext_vector_type(4))) float f32x4;

#define NEG (-1e30f)
#define LN2 0.6931471805599453f
#define INV_LN2 1.4426950408889634f

// Problem sizes
#define B_N 16
#define T_N 500
#define E_N 1024
#define V_N 4000
#define L_N 100
#define S_N 201      // 2L+1
#define M_P 8064     // 63*128 padded rows
#define N_P 4096     // 32*128 padded vocab
#define LLP 104      // lab_lp row stride (blank + 100 labels, padded)

// ws layout (bytes)
#define OFF_A   0
#define OFF_BT  16515072UL   // 8064*1024*2
#define OFF_C   24903680UL   // + 4096*1024*2
#define OFF_LAB 90963968UL   // + 8064*4096*2

__device__ __forceinline__ u16 f2bf(float f) {
  u32 u = __float_as_uint(f);
  u += 0x7fffu + ((u >> 16) & 1u);   // RNE
  return (u16)(u >> 16);
}
__device__ __forceinline__ float bf2f(u16 h) {
  return __uint_as_float(((u32)h) << 16);
}
// log2-domain logaddexp: 2 transcendentals (exp2f -> native v_exp_f32)
__device__ __forceinline__ float lse2_2(float x, float y) {
  float m = fmaxf(x, y);
  float d = -fabsf(x - y);
  return m + __log2f(1.0f + exp2f(d));
}
// log2-domain 3-way logaddexp: 4 transcendentals
__device__ __forceinline__ float lse3_2(float x, float y, float z) {
  float m = fmaxf(fmaxf(x, y), z);
  return m + __log2f(exp2f(x - m) + exp2f(y - m) + exp2f(z - m));
}

// K1: cast hs [8000][1024] f32 -> A bf16 [8064][1024] (pad rows zero); zero d_out
__global__ __launch_bounds__(256) void castA(const float* __restrict__ hs,
                                             u16* __restrict__ A,
                                             float* __restrict__ out) {
  int idx = blockIdx.x * 256 + threadIdx.x;   // < 2064384 (float4 groups)
  if (idx == 0) out[0] = 0.f;
  int row = idx >> 8;                          // (idx*4) >> 10
  float4 x;
  if (row < B_N * T_N) x = ((const float4*)hs)[idx];
  else x = make_float4(0.f, 0.f, 0.f, 0.f);
  ushort4 o;
  o.x = f2bf(x.x); o.y = f2bf(x.y); o.z = f2bf(x.z); o.w = f2bf(x.w);
  ((ushort4*)A)[idx] = o;
}

// K2: transpose-cast W [1024][4000] f32 -> Bt bf16 [4096][1024] (pad cols zero)
__global__ __launch_bounds__(256) void castB(const float* __restrict__ W,
                                             u16* __restrict__ Bt) {
  __shared__ float tile[32][33];
  int v0 = blockIdx.x * 32;   // vocab
  int e0 = blockIdx.y * 32;   // embed
  int tx = threadIdx.x & 31, ty = threadIdx.x >> 5;  // 32 x 8
#pragma unroll
  for (int i = 0; i < 4; ++i) {
    int e = e0 + ty * 4 + i;
    int v = v0 + tx;
    tile[ty * 4 + i][tx] = (v < V_N) ? W[e * V_N + v] : 0.f;
  }
  __syncthreads();
#pragma unroll
  for (int i = 0; i < 4; ++i) {
    int vloc = ty * 4 + i;
    Bt[(size_t)(v0 + vloc) * 1024 + (e0 + tx)] = f2bf(tile[tx][vloc]);
  }
}

// K3: 128x128x32 bf16 MFMA GEMM, C = A * Bt^T  (logits, stored bf16, no bias)
__global__ __launch_bounds__(256, 2) void gemm_bf16(const u16* __restrict__ A,
                                                    const u16* __restrict__ Bt,
                                                    u16* __restrict__ C) {
  __shared__ __align__(16) u16 As[128 * 32];
  __shared__ __align__(16) u16 Bs[128 * 32];
  const int tid = threadIdx.x;
  const int lane = tid & 63;
  const int w = tid >> 6;          // wave 0..3
  const int wm = w >> 1, wn = w & 1;
  const size_t m0 = (size_t)blockIdx.y * 128;
  const size_t n0 = (size_t)blockIdx.x * 128;

  const int sr = lane >> 2;            // 0..15
  const int sc = (lane & 3) << 3;      // 0,8,16,24 (bf16 elems)
  const u16* gA = A + (m0 + (size_t)(w * 32 + sr)) * 1024 + sc;
  const u16* gB = Bt + (n0 + (size_t)(w * 32 + sr)) * 1024 + sc;
  u16* sA = &As[(w * 32) * 32];
  u16* sB = &Bs[(w * 32) * 32];

  f32x4 acc[4][4];
#pragma unroll
  for (int i = 0; i < 4; ++i)
#pragma unroll
    for (int j = 0; j < 4; ++j) acc[i][j] = (f32x4){0.f, 0.f, 0.f, 0.f};

  const int fr = lane & 15;
  const int fq = (lane >> 4) << 3;     // k offset 0/8/16/24
  const u16* rA = &As[(wm * 64 + fr) * 32 + fq];
  const u16* rB = &Bs[(wn * 64 + fr) * 32 + fq];

  for (int kt = 0; kt < 1024; kt += 32) {
#pragma unroll
    for (int u = 0; u < 2; ++u) {
      __builtin_amdgcn_global_load_lds(
          (const __attribute__((address_space(1))) void*)(gA + u * 16 * 1024 + kt),
          (__attribute__((address_space(3))) void*)(sA + u * 16 * 32), 16, 0, 0);
      __builtin_amdgcn_global_load_lds(
          (const __attribute__((address_space(1))) void*)(gB + u * 16 * 1024 + kt),
          (__attribute__((address_space(3))) void*)(sB + u * 16 * 32), 16, 0, 0);
    }
    __syncthreads();
    short8 af[4], bfr[4];
#pragma unroll
    for (int i = 0; i < 4; ++i) af[i] = *(const short8*)(rA + i * 16 * 32);
#pragma unroll
    for (int j = 0; j < 4; ++j) bfr[j] = *(const short8*)(rB + j * 16 * 32);
#pragma unroll
    for (int i = 0; i < 4; ++i)
#pragma unroll
      for (int j = 0; j < 4; ++j)
        acc[i][j] = __builtin_amdgcn_mfma_f32_16x16x32_bf16(af[i], bfr[j],
                                                            acc[i][j], 0, 0, 0);
    __syncthreads();
  }

  const int cq = lane >> 4;
  const int cc = lane & 15;
#pragma unroll
  for (int i = 0; i < 4; ++i)
#pragma unroll
    for (int j = 0; j < 4; ++j) {
      size_t rr = m0 + wm * 64 + i * 16 + cq * 4;
      size_t nn = n0 + wn * 64 + j * 16 + cc;
      u16* o = C + rr * N_P + nn;
#pragma unroll
      for (int g = 0; g < 4; ++g) o[(size_t)g * N_P] = f2bf(acc[i][j][g]);
    }
}

// K4: per-row logsumexp over V + gather label log-probs -> lab_lp [8000][104]
// Output is scaled by 1/ln2 (log2 domain) for the DP kernel.
__global__ __launch_bounds__(256) void rowstat(const u16* __restrict__ C,
                                               const float* __restrict__ bias,
                                               const int* __restrict__ ys,
                                               float* __restrict__ lab) {
  int r = blockIdx.x;          // 0..7999
  int tid = threadIdx.x;
  const u16* row = C + (size_t)r * N_P;
  float v[16];
  float mx = NEG;
#pragma unroll
  for (int u = 0; u < 16; ++u) {
    int c = tid + (u << 8);
    float x = (c < V_N) ? bf2f(row[c]) + bias[c] : NEG;
    v[u] = x;
    mx = fmaxf(mx, x);
  }
#pragma unroll
  for (int o = 32; o > 0; o >>= 1) mx = fmaxf(mx, __shfl_xor(mx, o));
  __shared__ float sm[4], ss[4];
  int w = tid >> 6;
  if ((tid & 63) == 0) sm[w] = mx;
  __syncthreads();
  mx = fmaxf(fmaxf(sm[0], sm[1]), fmaxf(sm[2], sm[3]));
  float s = 0.f;
#pragma unroll
  for (int u = 0; u < 16; ++u) s += __expf(v[u] - mx);
#pragma unroll
  for (int o = 32; o > 0; o >>= 1) s += __shfl_xor(s, o);
  if ((tid & 63) == 0) ss[w] = s;
  __syncthreads();
  float lse = mx + __logf(ss[0] + ss[1] + ss[2] + ss[3]);
  if (tid < 1 + L_N) {
    int b = r / T_N;
    int lab_id = (tid == 0) ? 0 : max(ys[b * L_N + tid - 1], 0);
    lab[(size_t)r * LLP + tid] = (bf2f(row[lab_id]) + bias[lab_id] - lse) * INV_LN2;
  }
}

// K5: CTC forward DP, log2 domain. One wave per batch; lane L holds states
// 4L..4L+3 (blocked) -> ONE shuffle per step. 8-deep register ring prefetch
// of the per-step lab values (load for t+8 issues at step t: ~1200 cyc cover
// >= 900 cyc HBM-miss latency). Tail frozen via wave-uniform cndmask.
__global__ __launch_bounds__(64) void ctc_dp(const float* __restrict__ lab,
                                             const int* __restrict__ ys,
                                             const int* __restrict__ ilens,
                                             const int* __restrict__ olens,
                                             float* __restrict__ out) {
  int b = blockIdx.x;
  int L = threadIdx.x;
  const float* base = lab + (size_t)b * T_N * LLP;

  // label indices for this lane's odd states: s=4L+1 -> k0=2L, s=4L+3 -> k1=2L+1
  int k0 = 2 * L, k1 = 2 * L + 1;
  int k0c = min(k0, L_N - 1), k1c = min(k1, L_N - 1);
  int y0 = max(ys[b * L_N + k0c], 0);
  int y1 = max(ys[b * L_N + k1c], 0);
  int y0m = (k0 > 0) ? max(ys[b * L_N + min(k0 - 1, L_N - 1)], 0) : -1;
  bool allow1 = (y0 != 0) && (y0 != y0m);   // skip into s=4L+1 (lane 0: p3=NEG anyway)
  bool allow3 = (y1 != 0) && (y1 != y0);    // skip into s=4L+3
  int slotK0 = 1 + k0c, slotK1 = 1 + k1c;

  // t = 0 init (log2 domain): only s=0,1 live
  float a0 = (L == 0) ? base[0] : NEG;
  float a1 = (L == 0) ? base[1] : NEG;
  float a2 = NEG, a3 = NEG;

  int il = ilens[b];   // >= 250

  // 8-deep prefetch ring (static indices after unroll -> stays in VGPRs)
  float rB[8], rK0[8], rK1[8];
#pragma unroll
  for (int u = 0; u < 8; ++u) {
    int tt = min(1 + u, il - 1);
    const float* p = base + (size_t)tt * LLP;
    rB[u] = p[0]; rK0[u] = p[slotK0]; rK1[u] = p[slotK1];
  }

  for (int t0 = 1; t0 < il; t0 += 8) {
#pragma unroll
    for (int u = 0; u < 8; ++u) {
      int t = t0 + u;
      float lpB = rB[u], lpK0 = rK0[u], lpK1 = rK1[u];
      // refill slot u with row t+8 (clamped; clamped value only consumed dead)
      int tt = min(t + 8, il - 1);
      const float* p = base + (size_t)tt * LLP;
      rB[u] = p[0]; rK0[u] = p[slotK0]; rK1[u] = p[slotK1];

      float p3 = __shfl_up(a3, 1);
      if (L == 0) p3 = NEG;
      float p3m = allow1 ? p3 : NEG;
      float a1m = allow3 ? a1 : NEG;

      float n0 = lse2_2(a0, p3) + lpB;          // blank s=4L
      float n1 = lse3_2(a1, a0, p3m) + lpK0;    // label s=4L+1
      float n2 = lse2_2(a2, a1) + lpB;          // blank s=4L+2
      float n3 = lse3_2(a3, a2, a1m) + lpK1;    // label s=4L+3

      bool live = t < il;                        // wave-uniform freeze
      a0 = live ? n0 : a0;
      a1 = live ? n1 : a1;
      a2 = live ? n2 : a2;
      a3 = live ? n3 : a3;
    }
  }

  int ol = olens[b];
  int s1 = 2 * ol, s2 = 2 * ol - 1;   // s1 even, s2 odd; both <= 200
  int j1 = s1 & 3, j2 = s2 & 3;       // uniform across wave
  float t1 = (j1 == 0) ? a0 : a2;
  float t2 = (j2 == 1) ? a1 : a3;
  float x1 = __shfl(t1, s1 >> 2);
  float x2 = __shfl(t2, s2 >> 2);
  float ll = lse2_2(x1, x2) * LN2;    // back to natural log
  if (L == 0) atomicAdd(out, -ll * (1.0f / B_N));
}

extern "C" void kernel_launch(void* const* d_in, const int* in_sizes, int n_in,
                              void* d_out, int out_size, void* d_ws, size_t ws_size,
                              hipStream_t stream) {
  const float* hs    = (const float*)d_in[0];
  const float* W     = (const float*)d_in[1];
  const float* bias  = (const float*)d_in[2];
  const int*   ys    = (const int*)d_in[3];
  const int*   ilens = (const int*)d_in[4];
  const int*   olens = (const int*)d_in[5];
  char* ws = (char*)d_ws;
  u16*   A   = (u16*)(ws + OFF_A);
  u16*   Bt  = (u16*)(ws + OFF_BT);
  u16*   C   = (u16*)(ws + OFF_C);
  float* lab = (float*)(ws + OFF_LAB);
  float* out = (float*)d_out;

  castA<<<M_P * E_N / (256 * 4), 256, 0, stream>>>(hs, A, out);
  castB<<<dim3(N_P / 32, E_N / 32), 256, 0, stream>>>(W, Bt);
  gemm_bf16<<<dim3(N_P / 128, M_P / 128), 256, 0, stream>>>(A, Bt, C);
  rowstat<<<B_N * T_N, 256, 0, stream>>>(C, bias, ys, lab);
  ctc_dp<<<B_N, 64, 0, stream>>>(lab, ys, ilens, olens, out);
}

// Round 5
// 256.018 us; speedup vs baseline: 1.4728x; 1.2081x over previous
//
#include <hip/hip_runtime.h>

typedef unsigned short u16;
typedef unsigned int u32;
typedef unsigned char u8;
typedef __attribute__((ext_vector_type(4))) int int4v;
typedef __attribute__((ext_vector_type(8))) int int8v;
typedef __attribute__((ext_vector_type(4))) float f32x4;

#define NEG (-1e30f)
#define LN2 0.6931471805599453f
#define INV_LN2 1.4426950408889634f

// Problem sizes
#define B_N 16
#define T_N 500
#define E_N 1024
#define V_N 4000
#define L_N 100
#define M_P 8064     // 63*128 padded rows
#define N_P 4096     // 32*128 padded vocab
#define LLP 128      // lab_lp row stride in floats (512 B)

// ws layout (bytes)
#define OFF_A   0UL          // fp8 A  [8064][1024]  = 8,257,536
#define OFF_B   8257536UL    // fp8 Bt [4096][1024]  = 4,194,304
#define OFF_C   12451840UL   // bf16 C [8064][4096]  = 66,060,288
#define OFF_LAB 78512128UL   // f32 lab[8000][128]   = 4,096,000  (end 82.6 MB)

__device__ __forceinline__ u16 f2bf(float f) {
  u32 u = __float_as_uint(f);
  u += 0x7fffu + ((u >> 16) & 1u);   // RNE
  return (u16)(u >> 16);
}
__device__ __forceinline__ float bf2f(u16 h) {
  return __uint_as_float(((u32)h) << 16);
}
__device__ __forceinline__ float lse2_2(float x, float y) {
  float m = fmaxf(x, y);
  float d = -fabsf(x - y);
  return m + __log2f(1.0f + exp2f(d));
}
__device__ __forceinline__ float lse3_2(float x, float y, float z) {
  float m = fmaxf(fmaxf(x, y), z);
  return m + __log2f(exp2f(x - m) + exp2f(y - m) + exp2f(z - m));
}
__device__ __forceinline__ void gl_lds16(const void* g, void* l) {
  __builtin_amdgcn_global_load_lds((const __attribute__((address_space(1))) void*)g,
                                   (__attribute__((address_space(3))) void*)l, 16, 0, 0);
}

// K1: cast hs [8000][1024] f32 -> fp8 e4m3 A [8064][1024] (pad rows 0); zero d_out
__global__ __launch_bounds__(256) void castA(const float* __restrict__ hs,
                                             u32* __restrict__ Aq,
                                             float* __restrict__ out) {
  int idx = blockIdx.x * 256 + threadIdx.x;   // 4 elems per thread
  if (idx == 0) out[0] = 0.f;
  int row = idx >> 8;
  float4 x;
  if (row < B_N * T_N) x = ((const float4*)hs)[idx];
  else x = make_float4(0.f, 0.f, 0.f, 0.f);
  u32 p = __builtin_amdgcn_cvt_pk_fp8_f32(x.x, x.y, 0, false);
  p = __builtin_amdgcn_cvt_pk_fp8_f32(x.z, x.w, p, true);
  Aq[idx] = p;
}

// K2: transpose-cast W [1024][4000] f32 -> fp8 Bt [4096][1024], scaled x64
__global__ __launch_bounds__(256) void castB(const float* __restrict__ W,
                                             u8* __restrict__ Bq) {
  __shared__ float tile[32][33];
  int v0 = blockIdx.x * 32;   // vocab
  int e0 = blockIdx.y * 32;   // embed
  int tx = threadIdx.x & 31, ty = threadIdx.x >> 5;  // 32 x 8
#pragma unroll
  for (int i = 0; i < 4; ++i) {
    int e = e0 + ty * 4 + i;
    int v = v0 + tx;
    tile[ty * 4 + i][tx] = (v < V_N) ? W[e * V_N + v] : 0.f;
  }
  __syncthreads();
#pragma unroll
  for (int i = 0; i < 4; ++i) {
    int vloc = ty * 4 + i;
    float x = tile[tx][vloc] * 64.f;   // exact pow2 pre-scale into e4m3 range
    u32 p = __builtin_amdgcn_cvt_pk_fp8_f32(x, x, 0, false);
    Bq[(size_t)(v0 + vloc) * 1024 + (e0 + tx)] = (u8)(p & 0xff);
  }
}

// K3: 128x128x128 K-tile MX-fp8 MFMA GEMM (scales=2^0 -> plain fp8 at 2x rate).
// LDS: 16 groups of 8 rows x 128 B, group stride 1056 (32 B pad); within a row,
// chunk c (16 B) stored at slot c^(row&7) (XOR swizzle; staging lane picks its
// global chunk to match, global coalescing preserved within the 128 B row).
__global__ __launch_bounds__(256, 2) void gemm_fp8(const u8* __restrict__ A,
                                                   const u8* __restrict__ Bq,
                                                   u16* __restrict__ C) {
  __shared__ __align__(16) u8 As[16 * 1056];
  __shared__ __align__(16) u8 Bs[16 * 1056];
  const int tid = threadIdx.x;
  const int lane = tid & 63;
  const int w = tid >> 6;          // wave 0..3
  const int wm = w >> 1, wn = w & 1;
  const size_t m0 = (size_t)blockIdx.y * 128;
  const size_t n0 = (size_t)blockIdx.x * 128;

  const int lr = lane >> 3;        // row in 8-row group
  const int lc = lane & 7;         // LDS slot
  const int gc = lc ^ lr;          // global chunk this lane fetches
  const u8* gA = A + (m0 + w * 32 + lr) * 1024 + gc * 16;
  const u8* gB = Bq + (n0 + w * 32 + lr) * 1024 + gc * 16;
  u8* sA = As + (w * 4) * 1056;
  u8* sB = Bs + (w * 4) * 1056;

  f32x4 acc[4][4];
#pragma unroll
  for (int i = 0; i < 4; ++i)
#pragma unroll
    for (int j = 0; j < 4; ++j) acc[i][j] = (f32x4){0.f, 0.f, 0.f, 0.f};

  const int fr = lane & 15, q = lane >> 4;
  const int c0 = ((2 * q) ^ (fr & 7)) * 16;       // swizzled chunk addrs
  const int c1 = ((2 * q + 1) ^ (fr & 7)) * 16;
  const int rA0 = wm * 64 + fr;
  const int rB0 = wn * 64 + fr;

  for (int kt = 0; kt < 1024; kt += 128) {
#pragma unroll
    for (int u = 0; u < 4; ++u) {
      gl_lds16(gA + (size_t)u * 8192 + kt, sA + u * 1056);
      gl_lds16(gB + (size_t)u * 8192 + kt, sB + u * 1056);
    }
    __syncthreads();
    int8v af[4], bf[4];
#pragma unroll
    for (int i = 0; i < 4; ++i) {
      int r = rA0 + i * 16;
      const u8* p = As + (r >> 3) * 1056 + (r & 7) * 128;
      int4v lo = *(const int4v*)(p + c0);
      int4v hi = *(const int4v*)(p + c1);
      af[i] = (int8v){lo[0], lo[1], lo[2], lo[3], hi[0], hi[1], hi[2], hi[3]};
    }
#pragma unroll
    for (int j = 0; j < 4; ++j) {
      int r = rB0 + j * 16;
      const u8* p = Bs + (r >> 3) * 1056 + (r & 7) * 128;
      int4v lo = *(const int4v*)(p + c0);
      int4v hi = *(const int4v*)(p + c1);
      bf[j] = (int8v){lo[0], lo[1], lo[2], lo[3], hi[0], hi[1], hi[2], hi[3]};
    }
#pragma unroll
    for (int i = 0; i < 4; ++i)
#pragma unroll
      for (int j = 0; j < 4; ++j)
        acc[i][j] = __builtin_amdgcn_mfma_scale_f32_16x16x128_f8f6f4(
            af[i], bf[j], acc[i][j], 0, 0,        // cbsz=fp8, blgp=fp8
            0, 0x7F7F7F7F, 0, 0x7F7F7F7F);        // E8M0 127 = 2^0
    __syncthreads();
  }

  // C/D: col=lane&15, row=(lane>>4)*4+reg; undo W x64 pre-scale
  const int cq = lane >> 4, cc = lane & 15;
#pragma unroll
  for (int i = 0; i < 4; ++i)
#pragma unroll
    for (int j = 0; j < 4; ++j) {
      size_t rr = m0 + wm * 64 + i * 16 + cq * 4;
      size_t nn = n0 + wn * 64 + j * 16 + cc;
      u16* o = C + rr * N_P + nn;
#pragma unroll
      for (int g = 0; g < 4; ++g) o[(size_t)g * N_P] = f2bf(acc[i][j][g] * 0.015625f);
    }
}

// K4: per-row logsumexp over V + gather label log-probs -> lab [8000][128] (log2 dom)
__global__ __launch_bounds__(256) void rowstat(const u16* __restrict__ C,
                                               const float* __restrict__ bias,
                                               const int* __restrict__ ys,
                                               float* __restrict__ lab) {
  int r = blockIdx.x;
  int tid = threadIdx.x;
  const u16* row = C + (size_t)r * N_P;
  float v[16];
  float mx = NEG;
#pragma unroll
  for (int u = 0; u < 16; ++u) {
    int c = tid + (u << 8);
    float x = (c < V_N) ? bf2f(row[c]) + bias[c] : NEG;
    v[u] = x;
    mx = fmaxf(mx, x);
  }
#pragma unroll
  for (int o = 32; o > 0; o >>= 1) mx = fmaxf(mx, __shfl_xor(mx, o));
  __shared__ float sm[4], ss[4];
  int w = tid >> 6;
  if ((tid & 63) == 0) sm[w] = mx;
  __syncthreads();
  mx = fmaxf(fmaxf(sm[0], sm[1]), fmaxf(sm[2], sm[3]));
  float s = 0.f;
#pragma unroll
  for (int u = 0; u < 16; ++u) s += __expf(v[u] - mx);
#pragma unroll
  for (int o = 32; o > 0; o >>= 1) s += __shfl_xor(s, o);
  if ((tid & 63) == 0) ss[w] = s;
  __syncthreads();
  float lse = mx + __logf(ss[0] + ss[1] + ss[2] + ss[3]);
  if (tid < 1 + L_N) {
    int b = r / T_N;
    int lab_id = (tid == 0) ? 0 : max(ys[b * L_N + tid - 1], 0);
    lab[(size_t)r * LLP + tid] = (bf2f(row[lab_id]) + bias[lab_id] - lse) * INV_LN2;
  }
}

// K5: CTC DP, log2 domain, blocked states (1 shuffle/step). lab rows stream
// through an LDS quad-buffer via async global_load_lds DMA; s_waitcnt vmcnt(8)
// keeps 2 chunks (16 rows) in flight -> structural prefetch the compiler
// cannot sink. Single wave per block: no barriers needed.
__global__ __launch_bounds__(64) void ctc_dp(const float* __restrict__ lab,
                                             const int* __restrict__ ys,
                                             const int* __restrict__ ilens,
                                             const int* __restrict__ olens,
                                             float* __restrict__ out) {
  __shared__ float buf[4][1024];   // 4 chunks x 8 rows x 128 floats
  int b = blockIdx.x;
  int L = threadIdx.x;
  const char* gb = (const char*)(lab + (size_t)b * T_N * LLP);

  int k0 = 2 * L, k1 = 2 * L + 1;
  int k0c = min(k0, L_N - 1), k1c = min(k1, L_N - 1);
  int y0 = max(ys[b * L_N + k0c], 0);
  int y1 = max(ys[b * L_N + k1c], 0);
  int y0m = (k0 > 0) ? max(ys[b * L_N + min(k0 - 1, L_N - 1)], 0) : -1;
  bool allow1 = (y0 != 0) && (y0 != y0m);
  bool allow3 = (y1 != 0) && (y1 != y0);
  int slotK0 = 1 + k0c, slotK1 = 1 + k1c;

  const float* r0p = (const float*)gb;   // t=0 row
  float a0 = (L == 0) ? r0p[0] : NEG;
  float a1 = (L == 0) ? r0p[1] : NEG;
  float a2 = NEG, a3 = NEG;
  int il = ilens[b];   // >= 250

  // preload 3 chunks: phase p <- rows [1+8p, 9+8p)
#pragma unroll
  for (int p = 0; p < 3; ++p) {
    const char* s = gb + (size_t)(1 + 8 * p) * 512 + L * 16;
#pragma unroll
    for (int c = 0; c < 4; ++c) gl_lds16(s + c * 1024, &buf[p][c * 256]);
  }

  int phase = 0;
  for (int t0 = 1; t0 < il; t0 += 8) {
    asm volatile("s_waitcnt vmcnt(8)" ::: "memory");   // current chunk landed
    const float* bp = buf[phase & 3];
    float rB[8], rK0[8], rK1[8];
#pragma unroll
    for (int u = 0; u < 8; ++u) {
      rB[u] = bp[u * 128];
      rK0[u] = bp[u * 128 + slotK0];
      rK1[u] = bp[u * 128 + slotK1];
    }
#pragma unroll
    for (int u = 0; u < 8; ++u) {
      int t = t0 + u;
      float p3 = __shfl_up(a3, 1);
      if (L == 0) p3 = NEG;
      float p3m = allow1 ? p3 : NEG;
      float a1m = allow3 ? a1 : NEG;
      float n0 = lse2_2(a0, p3) + rB[u];
      float n1 = lse3_2(a1, a0, p3m) + rK0[u];
      float n2 = lse2_2(a2, a1) + rB[u];
      float n3 = lse3_2(a3, a2, a1m) + rK1[u];
      bool live = t < il;   // wave-uniform freeze (garbage rows masked here)
      a0 = live ? n0 : a0; a1 = live ? n1 : a1;
      a2 = live ? n2 : a2; a3 = live ? n3 : a3;
    }
    asm volatile("" ::: "memory");
    {   // refill phase+3 with rows [t0+24, t0+32) (OOB-past-il rows never live)
      const char* s = gb + (size_t)(t0 + 24) * 512 + L * 16;
      float* d = buf[(phase + 3) & 3];
#pragma unroll
      for (int c = 0; c < 4; ++c) gl_lds16(s + c * 1024, &d[c * 256]);
    }
    phase = (phase + 1) & 3;
  }
  asm volatile("s_waitcnt vmcnt(0)" ::: "memory");   // drain DMA before endpgm

  int ol = olens[b];
  int s1 = 2 * ol, s2 = 2 * ol - 1;
  int j1 = s1 & 3, j2 = s2 & 3;
  float t1 = (j1 == 0) ? a0 : a2;
  float t2 = (j2 == 1) ? a1 : a3;
  float x1 = __shfl(t1, s1 >> 2);
  float x2 = __shfl(t2, s2 >> 2);
  float ll = lse2_2(x1, x2) * LN2;
  if (L == 0) atomicAdd(out, -ll * (1.0f / B_N));
}

extern "C" void kernel_launch(void* const* d_in, const int* in_sizes, int n_in,
                              void* d_out, int out_size, void* d_ws, size_t ws_size,
                              hipStream_t stream) {
  const float* hs    = (const float*)d_in[0];
  const float* W     = (const float*)d_in[1];
  const float* bias  = (const float*)d_in[2];
  const int*   ys    = (const int*)d_in[3];
  const int*   ilens = (const int*)d_in[4];
  const int*   olens = (const int*)d_in[5];
  char* ws = (char*)d_ws;
  u8*    Aq  = (u8*)(ws + OFF_A);
  u8*    Bq  = (u8*)(ws + OFF_B);
  u16*   C   = (u16*)(ws + OFF_C);
  float* lab = (float*)(ws + OFF_LAB);
  float* out = (float*)d_out;

  castA<<<M_P * E_N / (256 * 4), 256, 0, stream>>>(hs, (u32*)Aq, out);
  castB<<<dim3(N_P / 32, E_N / 32), 256, 0, stream>>>(W, Bq);
  gemm_fp8<<<dim3(N_P / 128, M_P / 128), 256, 0, stream>>>(Aq, Bq, C);
  rowstat<<<B_N * T_N, 256, 0, stream>>>(C, bias, ys, lab);
  ctc_dp<<<B_N, 64, 0, stream>>>(lab, ys, ilens, olens, out);
}

// Round 6
// 247.944 us; speedup vs baseline: 1.5208x; 1.0326x over previous
//
#include <hip/hip_runtime.h>

typedef unsigned short u16;
typedef unsigned int u32;
typedef unsigned char u8;
typedef __attribute__((ext_vector_type(4))) int int4v;
typedef __attribute__((ext_vector_type(8))) int int8v;
typedef __attribute__((ext_vector_type(4))) float f32x4;

#define NEG (-1e30f)
#define LN2 0.6931471805599453f
#define INV_LN2 1.4426950408889634f

// Problem sizes
#define B_N 16
#define T_N 500
#define E_N 1024
#define V_N 4000
#define L_N 100
#define M_P 8064     // 63*128 padded rows
#define N_P 4096     // 32*128 padded vocab
#define LLP 128      // lab_lp row stride in floats (512 B)

// ws layout (bytes)
#define OFF_A   0UL          // fp8 A  [8064][1024]  = 8,257,536
#define OFF_B   8257536UL    // fp8 Bt [4096][1024]  = 4,194,304
#define OFF_C   12451840UL   // bf16 C [8064][4096]  = 66,060,288
#define OFF_LAB 78512128UL   // f32 lab[8000][128]   = 4,096,000  (end 82.6 MB)

__device__ __forceinline__ u16 f2bf(float f) {
  u32 u = __float_as_uint(f);
  u += 0x7fffu + ((u >> 16) & 1u);   // RNE
  return (u16)(u >> 16);
}
__device__ __forceinline__ float bf2f(u16 h) {
  return __uint_as_float(((u32)h) << 16);
}
__device__ __forceinline__ float lse2_2(float x, float y) {
  float m = fmaxf(x, y);
  float d = -fabsf(x - y);
  return m + __log2f(1.0f + exp2f(d));
}
__device__ __forceinline__ float lse3_2(float x, float y, float z) {
  float m = fmaxf(fmaxf(x, y), z);
  return m + __log2f(exp2f(x - m) + exp2f(y - m) + exp2f(z - m));
}
__device__ __forceinline__ void gl_lds16(const void* g, void* l) {
  __builtin_amdgcn_global_load_lds((const __attribute__((address_space(1))) void*)g,
                                   (__attribute__((address_space(3))) void*)l, 16, 0, 0);
}
// lane L <- lane L-1 via DPP WF_SHR1 (pure VALU, ~3 cyc; no LDS round-trip).
// Lane 0 (no source) takes `fill`.
__device__ __forceinline__ float dpp_shr1(float x, float fill) {
  int r = __builtin_amdgcn_update_dpp(__float_as_int(fill), __float_as_int(x),
                                      0x138, 0xF, 0xF, false);
  return __int_as_float(r);
}

// K1: cast hs [8000][1024] f32 -> fp8 e4m3 A [8064][1024] (pad rows 0); zero d_out
__global__ __launch_bounds__(256) void castA(const float* __restrict__ hs,
                                             u32* __restrict__ Aq,
                                             float* __restrict__ out) {
  int idx = blockIdx.x * 256 + threadIdx.x;   // 4 elems per thread
  if (idx == 0) out[0] = 0.f;
  int row = idx >> 8;
  float4 x;
  if (row < B_N * T_N) x = ((const float4*)hs)[idx];
  else x = make_float4(0.f, 0.f, 0.f, 0.f);
  u32 p = __builtin_amdgcn_cvt_pk_fp8_f32(x.x, x.y, 0, false);
  p = __builtin_amdgcn_cvt_pk_fp8_f32(x.z, x.w, p, true);
  Aq[idx] = p;
}

// K2: transpose-cast W [1024][4000] f32 -> fp8 Bt [4096][1024], scaled x64
__global__ __launch_bounds__(256) void castB(const float* __restrict__ W,
                                             u8* __restrict__ Bq) {
  __shared__ float tile[32][33];
  int v0 = blockIdx.x * 32;   // vocab
  int e0 = blockIdx.y * 32;   // embed
  int tx = threadIdx.x & 31, ty = threadIdx.x >> 5;  // 32 x 8
#pragma unroll
  for (int i = 0; i < 4; ++i) {
    int e = e0 + ty * 4 + i;
    int v = v0 + tx;
    tile[ty * 4 + i][tx] = (v < V_N) ? W[e * V_N + v] : 0.f;
  }
  __syncthreads();
#pragma unroll
  for (int i = 0; i < 4; ++i) {
    int vloc = ty * 4 + i;
    float x = tile[tx][vloc] * 64.f;   // exact pow2 pre-scale into e4m3 range
    u32 p = __builtin_amdgcn_cvt_pk_fp8_f32(x, x, 0, false);
    Bq[(size_t)(v0 + vloc) * 1024 + (e0 + tx)] = (u8)(p & 0xff);
  }
}

// K3: 128x128x128 K-tile MX-fp8 MFMA GEMM (scales=2^0 -> plain fp8 at 2x rate).
__global__ __launch_bounds__(256, 2) void gemm_fp8(const u8* __restrict__ A,
                                                   const u8* __restrict__ Bq,
                                                   u16* __restrict__ C) {
  __shared__ __align__(16) u8 As[16 * 1056];
  __shared__ __align__(16) u8 Bs[16 * 1056];
  const int tid = threadIdx.x;
  const int lane = tid & 63;
  const int w = tid >> 6;          // wave 0..3
  const int wm = w >> 1, wn = w & 1;
  const size_t m0 = (size_t)blockIdx.y * 128;
  const size_t n0 = (size_t)blockIdx.x * 128;

  const int lr = lane >> 3;        // row in 8-row group
  const int lc = lane & 7;         // LDS slot
  const int gc = lc ^ lr;          // global chunk this lane fetches
  const u8* gA = A + (m0 + w * 32 + lr) * 1024 + gc * 16;
  const u8* gB = Bq + (n0 + w * 32 + lr) * 1024 + gc * 16;
  u8* sA = As + (w * 4) * 1056;
  u8* sB = Bs + (w * 4) * 1056;

  f32x4 acc[4][4];
#pragma unroll
  for (int i = 0; i < 4; ++i)
#pragma unroll
    for (int j = 0; j < 4; ++j) acc[i][j] = (f32x4){0.f, 0.f, 0.f, 0.f};

  const int fr = lane & 15, q = lane >> 4;
  const int c0 = ((2 * q) ^ (fr & 7)) * 16;       // swizzled chunk addrs
  const int c1 = ((2 * q + 1) ^ (fr & 7)) * 16;
  const int rA0 = wm * 64 + fr;
  const int rB0 = wn * 64 + fr;

  for (int kt = 0; kt < 1024; kt += 128) {
#pragma unroll
    for (int u = 0; u < 4; ++u) {
      gl_lds16(gA + (size_t)u * 8192 + kt, sA + u * 1056);
      gl_lds16(gB + (size_t)u * 8192 + kt, sB + u * 1056);
    }
    __syncthreads();
    int8v af[4], bf[4];
#pragma unroll
    for (int i = 0; i < 4; ++i) {
      int r = rA0 + i * 16;
      const u8* p = As + (r >> 3) * 1056 + (r & 7) * 128;
      int4v lo = *(const int4v*)(p + c0);
      int4v hi = *(const int4v*)(p + c1);
      af[i] = (int8v){lo[0], lo[1], lo[2], lo[3], hi[0], hi[1], hi[2], hi[3]};
    }
#pragma unroll
    for (int j = 0; j < 4; ++j) {
      int r = rB0 + j * 16;
      const u8* p = Bs + (r >> 3) * 1056 + (r & 7) * 128;
      int4v lo = *(const int4v*)(p + c0);
      int4v hi = *(const int4v*)(p + c1);
      bf[j] = (int8v){lo[0], lo[1], lo[2], lo[3], hi[0], hi[1], hi[2], hi[3]};
    }
#pragma unroll
    for (int i = 0; i < 4; ++i)
#pragma unroll
      for (int j = 0; j < 4; ++j)
        acc[i][j] = __builtin_amdgcn_mfma_scale_f32_16x16x128_f8f6f4(
            af[i], bf[j], acc[i][j], 0, 0,        // cbsz=fp8, blgp=fp8
            0, 0x7F7F7F7F, 0, 0x7F7F7F7F);        // E8M0 127 = 2^0
    __syncthreads();
  }

  // C/D: col=lane&15, row=(lane>>4)*4+reg; undo W x64 pre-scale
  const int cq = lane >> 4, cc = lane & 15;
#pragma unroll
  for (int i = 0; i < 4; ++i)
#pragma unroll
    for (int j = 0; j < 4; ++j) {
      size_t rr = m0 + wm * 64 + i * 16 + cq * 4;
      size_t nn = n0 + wn * 64 + j * 16 + cc;
      u16* o = C + rr * N_P + nn;
#pragma unroll
      for (int g = 0; g < 4; ++g) o[(size_t)g * N_P] = f2bf(acc[i][j][g] * 0.015625f);
    }
}

// K4: per-row logsumexp over V + gather label log-probs -> lab [8000][128] (log2 dom)
__global__ __launch_bounds__(256) void rowstat(const u16* __restrict__ C,
                                               const float* __restrict__ bias,
                                               const int* __restrict__ ys,
                                               float* __restrict__ lab) {
  int r = blockIdx.x;
  int tid = threadIdx.x;
  const u16* row = C + (size_t)r * N_P;
  float v[16];
  float mx = NEG;
#pragma unroll
  for (int u = 0; u < 16; ++u) {
    int c = tid + (u << 8);
    float x = (c < V_N) ? bf2f(row[c]) + bias[c] : NEG;
    v[u] = x;
    mx = fmaxf(mx, x);
  }
#pragma unroll
  for (int o = 32; o > 0; o >>= 1) mx = fmaxf(mx, __shfl_xor(mx, o));
  __shared__ float sm[4], ss[4];
  int w = tid >> 6;
  if ((tid & 63) == 0) sm[w] = mx;
  __syncthreads();
  mx = fmaxf(fmaxf(sm[0], sm[1]), fmaxf(sm[2], sm[3]));
  float s = 0.f;
#pragma unroll
  for (int u = 0; u < 16; ++u) s += __expf(v[u] - mx);
#pragma unroll
  for (int o = 32; o > 0; o >>= 1) s += __shfl_xor(s, o);
  if ((tid & 63) == 0) ss[w] = s;
  __syncthreads();
  float lse = mx + __logf(ss[0] + ss[1] + ss[2] + ss[3]);
  if (tid < 1 + L_N) {
    int b = r / T_N;
    int lab_id = (tid == 0) ? 0 : max(ys[b * L_N + tid - 1], 0);
    lab[(size_t)r * LLP + tid] = (bf2f(row[lab_id]) + bias[lab_id] - lse) * INV_LN2;
  }
}

// K5: CTC DP, log2 domain, blocked states. Cross-lane shift via DPP WF_SHR1
// (VALU, ~3 cyc) instead of ds_bpermute (~120 cyc) -> critical path is the
// lse3 chain only. lab rows stream through an LDS quad-buffer via async
// global_load_lds DMA with explicit vmcnt throttling (structural prefetch).
__global__ __launch_bounds__(64) void ctc_dp(const float* __restrict__ lab,
                                             const int* __restrict__ ys,
                                             const int* __restrict__ ilens,
                                             const int* __restrict__ olens,
                                             float* __restrict__ out) {
  __shared__ float buf[4][1024];   // 4 chunks x 8 rows x 128 floats
  int b = blockIdx.x;
  int L = threadIdx.x;
  const char* gb = (const char*)(lab + (size_t)b * T_N * LLP);

  int k0 = 2 * L, k1 = 2 * L + 1;
  int k0c = min(k0, L_N - 1), k1c = min(k1, L_N - 1);
  int y0 = max(ys[b * L_N + k0c], 0);
  int y1 = max(ys[b * L_N + k1c], 0);
  int y0m = (k0 > 0) ? max(ys[b * L_N + min(k0 - 1, L_N - 1)], 0) : -1;
  bool allow1 = (y0 != 0) && (y0 != y0m);
  bool allow3 = (y1 != 0) && (y1 != y0);
  int slotK0 = 1 + k0c, slotK1 = 1 + k1c;

  const float* r0p = (const float*)gb;   // t=0 row
  float a0 = (L == 0) ? r0p[0] : NEG;
  float a1 = (L == 0) ? r0p[1] : NEG;
  float a2 = NEG, a3 = NEG;
  int il = ilens[b];   // >= 250

  // preload 3 chunks: phase p <- rows [1+8p, 9+8p)
#pragma unroll
  for (int p = 0; p < 3; ++p) {
    const char* s = gb + (size_t)(1 + 8 * p) * 512 + L * 16;
#pragma unroll
    for (int c = 0; c < 4; ++c) gl_lds16(s + c * 1024, &buf[p][c * 256]);
  }

  int phase = 0;
  for (int t0 = 1; t0 < il; t0 += 8) {
    asm volatile("s_waitcnt vmcnt(8)" ::: "memory");   // current chunk landed
    const float* bp = buf[phase & 3];
    float rB[8], rK0[8], rK1[8];
#pragma unroll
    for (int u = 0; u < 8; ++u) {
      rB[u] = bp[u * 128];
      rK0[u] = bp[u * 128 + slotK0];
      rK1[u] = bp[u * 128 + slotK1];
    }
#pragma unroll
    for (int u = 0; u < 8; ++u) {
      int t = t0 + u;
      float p3 = dpp_shr1(a3, NEG);           // lane L <- a3 of lane L-1
      float p3m = allow1 ? p3 : NEG;
      float a1m = allow3 ? a1 : NEG;
      float n0 = lse2_2(a0, p3) + rB[u];
      float n1 = lse3_2(a1, a0, p3m) + rK0[u];
      float n2 = lse2_2(a2, a1) + rB[u];
      float n3 = lse3_2(a3, a2, a1m) + rK1[u];
      bool live = t < il;   // wave-uniform freeze (garbage rows masked here)
      a0 = live ? n0 : a0; a1 = live ? n1 : a1;
      a2 = live ? n2 : a2; a3 = live ? n3 : a3;
    }
    asm volatile("" ::: "memory");
    {   // refill phase+3 with rows [t0+24, t0+32) (OOB-past-il rows never live)
      const char* s = gb + (size_t)(t0 + 24) * 512 + L * 16;
      float* d = buf[(phase + 3) & 3];
#pragma unroll
      for (int c = 0; c < 4; ++c) gl_lds16(s + c * 1024, &d[c * 256]);
    }
    phase = (phase + 1) & 3;
  }
  asm volatile("s_waitcnt vmcnt(0)" ::: "memory");   // drain DMA before endpgm

  int ol = olens[b];
  int s1 = 2 * ol, s2 = 2 * ol - 1;
  int j1 = s1 & 3, j2 = s2 & 3;
  float t1 = (j1 == 0) ? a0 : a2;
  float t2 = (j2 == 1) ? a1 : a3;
  float x1 = __shfl(t1, s1 >> 2);
  float x2 = __shfl(t2, s2 >> 2);
  float ll = lse2_2(x1, x2) * LN2;
  if (L == 0) atomicAdd(out, -ll * (1.0f / B_N));
}

extern "C" void kernel_launch(void* const* d_in, const int* in_sizes, int n_in,
                              void* d_out, int out_size, void* d_ws, size_t ws_size,
                              hipStream_t stream) {
  const float* hs    = (const float*)d_in[0];
  const float* W     = (const float*)d_in[1];
  const float* bias  = (const float*)d_in[2];
  const int*   ys    = (const int*)d_in[3];
  const int*   ilens = (const int*)d_in[4];
  const int*   olens = (const int*)d_in[5];
  char* ws = (char*)d_ws;
  u8*    Aq  = (u8*)(ws + OFF_A);
  u8*    Bq  = (u8*)(ws + OFF_B);
  u16*   C   = (u16*)(ws + OFF_C);
  float* lab = (float*)(ws + OFF_LAB);
  float* out = (float*)d_out;

  castA<<<M_P * E_N / (256 * 4), 256, 0, stream>>>(hs, (u32*)Aq, out);
  castB<<<dim3(N_P / 32, E_N / 32), 256, 0, stream>>>(W, Bq);
  gemm_fp8<<<dim3(N_P / 128, M_P / 128), 256, 0, stream>>>(Aq, Bq, C);
  rowstat<<<B_N * T_N, 256, 0, stream>>>(C, bias, ys, lab);
  ctc_dp<<<B_N, 64, 0, stream>>>(lab, ys, ilens, olens, out);
}